// Round 8
// baseline (1263.465 us; speedup 1.0000x reference)
//
#include <hip/hip_runtime.h>

#define N_NODES 100000
#define N_EDGES 1600000
#define IN_F 256
#define OUT_F 128
#define LDK 40  // padded k-stride (bf16 elems) for LDS tiles

// bucketed counting sort params: bucket = 64 destination nodes
#define NBUCK 1563           // ceil(N_NODES / 64)
#define NCHUNK 128           // edge chunks (one block each)
#define CHUNK_E (N_EDGES / NCHUNK)  // 12500
#define NSCAN (NBUCK * NCHUNK)      // 200064 count-matrix entries
#define ASTRIDE 132          // LDS accumulator row stride (floats)

typedef __attribute__((ext_vector_type(8))) short bf16x8;
typedef __attribute__((ext_vector_type(4))) float f32x4;

__device__ __forceinline__ unsigned short f2bf(float f) {
    unsigned u = __float_as_uint(f);
    unsigned r = u + 0x7fffu + ((u >> 16) & 1u);  // RNE
    return (unsigned short)(r >> 16);
}

// ---------------------------------------------------------------------------
// wt[col][k] (bf16) = w[k][col]
// ---------------------------------------------------------------------------
__global__ __launch_bounds__(256) void wtrans_kernel(const float* __restrict__ w,
                                                     unsigned short* __restrict__ wt) {
    int c = blockIdx.x;
    int k = threadIdx.x;
    wt[c * IN_F + k] = f2bf(w[k * OUT_F + c]);
}

// ---------------------------------------------------------------------------
// GEMM: support_bf16[N][128] = bf16(x) @ bf16(w). (unchanged)
// ---------------------------------------------------------------------------
__global__ __launch_bounds__(256) void gemm_mfma_kernel(const float* __restrict__ x,
                                                        const unsigned short* __restrict__ wt,
                                                        unsigned short* __restrict__ support) {
    __shared__ unsigned short xs[128 * LDK];
    __shared__ unsigned short ws[128 * LDK];

    const int tid = threadIdx.x;
    const int lane = tid & 63;
    const int wv = tid >> 6;
    const int wr = (wv >> 1) * 64;
    const int wc = (wv & 1) * 64;
    const int row0 = blockIdx.x * 128;
    const int l15 = lane & 15;
    const int kg = (lane >> 4) * 8;

    f32x4 acc[4][4];
#pragma unroll
    for (int m = 0; m < 4; ++m)
#pragma unroll
        for (int n = 0; n < 4; ++n) acc[m][n] = (f32x4){0.f, 0.f, 0.f, 0.f};

    for (int kt = 0; kt < 8; ++kt) {
        __syncthreads();
#pragma unroll
        for (int i = 0; i < 4; ++i) {
            int idx = tid + 256 * i;
            int r = idx >> 3, q = idx & 7;
            int grow = row0 + r;
            if (grow > N_NODES - 1) grow = N_NODES - 1;
            float4 v = *reinterpret_cast<const float4*>(&x[(size_t)grow * IN_F + kt * 32 + q * 4]);
            ushort4 b;
            b.x = f2bf(v.x); b.y = f2bf(v.y); b.z = f2bf(v.z); b.w = f2bf(v.w);
            *reinterpret_cast<ushort4*>(&xs[r * LDK + q * 4]) = b;
        }
#pragma unroll
        for (int j = 0; j < 2; ++j) {
            int idx = tid + 256 * j;
            int c = idx >> 2, q = idx & 3;
            uint4 v = *reinterpret_cast<const uint4*>(&wt[c * IN_F + kt * 32 + q * 8]);
            *reinterpret_cast<uint4*>(&ws[c * LDK + q * 8]) = v;
        }
        __syncthreads();

        bf16x8 af[4], bfr[4];
#pragma unroll
        for (int m = 0; m < 4; ++m)
            af[m] = *reinterpret_cast<const bf16x8*>(&xs[(wr + m * 16 + l15) * LDK + kg]);
#pragma unroll
        for (int n = 0; n < 4; ++n)
            bfr[n] = *reinterpret_cast<const bf16x8*>(&ws[(wc + n * 16 + l15) * LDK + kg]);
#pragma unroll
        for (int m = 0; m < 4; ++m)
#pragma unroll
            for (int n = 0; n < 4; ++n)
                acc[m][n] = __builtin_amdgcn_mfma_f32_16x16x32_bf16(af[m], bfr[n], acc[m][n], 0, 0, 0);
    }

#pragma unroll
    for (int m = 0; m < 4; ++m) {
#pragma unroll
        for (int r = 0; r < 4; ++r) {
            int row = row0 + wr + m * 16 + (lane >> 4) * 4 + r;
            if (row < N_NODES) {
#pragma unroll
                for (int n = 0; n < 4; ++n) {
                    support[(size_t)row * OUT_F + wc + n * 16 + l15] = f2bf(acc[m][n][r]);
                }
            }
        }
    }
}

// ---------------------------------------------------------------------------
// Sort phase 1: per-chunk coarse histogram, counts[bucket][chunk].
// bucket = dst >> 6 (64 nodes per bucket).
// ---------------------------------------------------------------------------
__global__ __launch_bounds__(256) void count_kernel(const int* __restrict__ rowi,
                                                    int* __restrict__ counts) {
    __shared__ int hist[NBUCK];
    const int tid = threadIdx.x, c = blockIdx.x;
    for (int i = tid; i < NBUCK; i += 256) hist[i] = 0;
    __syncthreads();
    const int e0 = c * CHUNK_E;
    for (int i = tid; i < CHUNK_E; i += 256)
        atomicAdd(&hist[rowi[e0 + i] >> 6], 1);
    __syncthreads();
    for (int i = tid; i < NBUCK; i += 256) counts[i * NCHUNK + c] = hist[i];
}

__global__ __launch_bounds__(256) void scan1_kernel(int* __restrict__ data,
                                                    int* __restrict__ blocksums,
                                                    int n) {
    __shared__ int sdata[256];
    const int tid = threadIdx.x;
    const int base = blockIdx.x * 1024 + tid * 4;
    int v0 = (base + 0 < n) ? data[base + 0] : 0;
    int v1 = (base + 1 < n) ? data[base + 1] : 0;
    int v2 = (base + 2 < n) ? data[base + 2] : 0;
    int v3 = (base + 3 < n) ? data[base + 3] : 0;
    int s1 = v0 + v1, s2 = s1 + v2, s3 = s2 + v3;
    sdata[tid] = s3;
    __syncthreads();
#pragma unroll
    for (int off = 1; off < 256; off <<= 1) {
        int t = (tid >= off) ? sdata[tid - off] : 0;
        __syncthreads();
        sdata[tid] += t;
        __syncthreads();
    }
    int excl = (tid == 0) ? 0 : sdata[tid - 1];
    if (base + 0 < n) data[base + 0] = excl;
    if (base + 1 < n) data[base + 1] = excl + v0;
    if (base + 2 < n) data[base + 2] = excl + s1;
    if (base + 3 < n) data[base + 3] = excl + s2;
    if (tid == 255) blocksums[blockIdx.x] = sdata[255];
}

// scan2: single block (256 threads) exclusive scan of nblk <= 256 block sums.
__global__ __launch_bounds__(256) void scan2_kernel(int* __restrict__ blocksums, int nblk) {
    __shared__ int sdata[256];
    const int tid = threadIdx.x;
    sdata[tid] = (tid < nblk) ? blocksums[tid] : 0;
    __syncthreads();
#pragma unroll
    for (int off = 1; off < 256; off <<= 1) {
        int t = (tid >= off) ? sdata[tid - off] : 0;
        __syncthreads();
        sdata[tid] += t;
        __syncthreads();
    }
    if (tid < nblk) blocksums[tid] = (tid == 0) ? 0 : sdata[tid - 1];
}

__global__ __launch_bounds__(256) void scan3_kernel(int* __restrict__ data,
                                                    const int* __restrict__ blocksums,
                                                    int n) {
    int i = blockIdx.x * 1024 + threadIdx.x * 4;
    int b = blocksums[blockIdx.x];
    if (i + 0 < n) data[i + 0] += b;
    if (i + 1 < n) data[i + 1] += b;
    if (i + 2 < n) data[i + 2] += b;
    if (i + 3 < n) data[i + 3] += b;
}

// ---------------------------------------------------------------------------
// Sort phase 2: coarse scatter into bucket-grouped order (no global atomics).
// tmp entry: x = (dst_low6 << 17) | col, y = val bits.
// ---------------------------------------------------------------------------
__global__ __launch_bounds__(256) void scatter1_kernel(const int* __restrict__ rowi,
                                                       const int* __restrict__ coli,
                                                       const float* __restrict__ val,
                                                       const int* __restrict__ bases,
                                                       uint2* __restrict__ tmp) {
    __shared__ int cur[NBUCK];
    const int tid = threadIdx.x, c = blockIdx.x;
    for (int i = tid; i < NBUCK; i += 256) cur[i] = bases[i * NCHUNK + c];
    __syncthreads();
    const int e0 = c * CHUNK_E;
    for (int i = tid; i < CHUNK_E; i += 256) {
        int e = e0 + i;
        int dst = rowi[e];
        int b = dst >> 6;
        int pos = atomicAdd(&cur[b], 1);
        tmp[pos] = make_uint2(((unsigned)(dst & 63) << 17) | (unsigned)coli[e],
                              __float_as_uint(val[e]));
    }
}

// ---------------------------------------------------------------------------
// accumulate: one block per 64-node bucket. Edge-parallel: 16 groups of 16
// lanes, each group streams 4 edges per iteration (16 gathers in flight per
// wave), accumulating into an LDS f32 accumulator via ds_add atomics.
// Flush once with bias via nontemporal stores. No per-node sort needed.
// ---------------------------------------------------------------------------
__global__ __launch_bounds__(256) void accum_bucket_kernel(const unsigned short* __restrict__ support,
                                                           const uint2* __restrict__ tmp,
                                                           const int* __restrict__ bases,
                                                           const float* __restrict__ bias,
                                                           float* __restrict__ out) {
    __shared__ float acc[64 * ASTRIDE];
    const int tid = threadIdx.x, b = blockIdx.x;
    const int g = tid >> 4;     // group 0..15
    const int l16 = tid & 15;   // feats l16*8 .. l16*8+7

    const int start = bases[b * NCHUNK];
    const int end = (b == NBUCK - 1) ? N_EDGES : bases[(b + 1) * NCHUNK];

    for (int i = tid; i < 64 * ASTRIDE; i += 256) acc[i] = 0.f;
    __syncthreads();

    for (int e0 = start + g * 4; e0 < end; e0 += 64) {
        // 4 edges per group in flight; guard with val=0 (adds 0 to node 0)
        uint2 p0 = (e0 + 0 < end) ? tmp[e0 + 0] : make_uint2(0u, 0u);
        uint2 p1 = (e0 + 1 < end) ? tmp[e0 + 1] : make_uint2(0u, 0u);
        uint2 p2 = (e0 + 2 < end) ? tmp[e0 + 2] : make_uint2(0u, 0u);
        uint2 p3 = (e0 + 3 < end) ? tmp[e0 + 3] : make_uint2(0u, 0u);
        uint4 s0 = *reinterpret_cast<const uint4*>(&support[(size_t)(p0.x & 0x1FFFFu) * OUT_F + l16 * 8]);
        uint4 s1 = *reinterpret_cast<const uint4*>(&support[(size_t)(p1.x & 0x1FFFFu) * OUT_F + l16 * 8]);
        uint4 s2 = *reinterpret_cast<const uint4*>(&support[(size_t)(p2.x & 0x1FFFFu) * OUT_F + l16 * 8]);
        uint4 s3 = *reinterpret_cast<const uint4*>(&support[(size_t)(p3.x & 0x1FFFFu) * OUT_F + l16 * 8]);

        {
            float v = __uint_as_float(p0.y);
            float* a = &acc[(p0.x >> 17) * ASTRIDE + l16 * 8];
            unsigned u[4] = {s0.x, s0.y, s0.z, s0.w};
#pragma unroll
            for (int q = 0; q < 4; ++q) {
                atomicAdd(a + 2 * q + 0, __uint_as_float(u[q] << 16) * v);
                atomicAdd(a + 2 * q + 1, __uint_as_float(u[q] & 0xffff0000u) * v);
            }
        }
        {
            float v = __uint_as_float(p1.y);
            float* a = &acc[(p1.x >> 17) * ASTRIDE + l16 * 8];
            unsigned u[4] = {s1.x, s1.y, s1.z, s1.w};
#pragma unroll
            for (int q = 0; q < 4; ++q) {
                atomicAdd(a + 2 * q + 0, __uint_as_float(u[q] << 16) * v);
                atomicAdd(a + 2 * q + 1, __uint_as_float(u[q] & 0xffff0000u) * v);
            }
        }
        {
            float v = __uint_as_float(p2.y);
            float* a = &acc[(p2.x >> 17) * ASTRIDE + l16 * 8];
            unsigned u[4] = {s2.x, s2.y, s2.z, s2.w};
#pragma unroll
            for (int q = 0; q < 4; ++q) {
                atomicAdd(a + 2 * q + 0, __uint_as_float(u[q] << 16) * v);
                atomicAdd(a + 2 * q + 1, __uint_as_float(u[q] & 0xffff0000u) * v);
            }
        }
        {
            float v = __uint_as_float(p3.y);
            float* a = &acc[(p3.x >> 17) * ASTRIDE + l16 * 8];
            unsigned u[4] = {s3.x, s3.y, s3.z, s3.w};
#pragma unroll
            for (int q = 0; q < 4; ++q) {
                atomicAdd(a + 2 * q + 0, __uint_as_float(u[q] << 16) * v);
                atomicAdd(a + 2 * q + 1, __uint_as_float(u[q] & 0xffff0000u) * v);
            }
        }
    }
    __syncthreads();

    // flush: thread t -> node (t>>2), feats (t&3)*32 .. +31
    const int n = tid >> 2;
    const int f0 = (tid & 3) * 32;
    const int node = b * 64 + n;
    if (node < N_NODES) {
#pragma unroll
        for (int i = 0; i < 8; ++i) {
            const float* ap = &acc[n * ASTRIDE + f0 + i * 4];
            float4 bv = *reinterpret_cast<const float4*>(&bias[f0 + i * 4]);
            f32x4 o = {ap[0] + bv.x, ap[1] + bv.y, ap[2] + bv.z, ap[3] + bv.w};
            __builtin_nontemporal_store(o, reinterpret_cast<f32x4*>(&out[(size_t)node * OUT_F + f0 + i * 4]));
        }
    }
}

extern "C" void kernel_launch(void* const* d_in, const int* in_sizes, int n_in,
                              void* d_out, int out_size, void* d_ws, size_t ws_size,
                              hipStream_t stream) {
    const float* x       = (const float*)d_in[0];
    const float* weight  = (const float*)d_in[1];
    const float* bias    = (const float*)d_in[2];
    const float* adj_val = (const float*)d_in[3];
    const int*   adj_row = (const int*)d_in[4];
    const int*   adj_col = (const int*)d_in[5];
    float* out = (float*)d_out;

    // workspace layout (~39 MB):
    //   support : 12.8M ushort (25.6 MB)
    //   wt      : 32768 ushort (64 KB)
    //   counts  : 200064 int (scanned in place -> bases)
    //   blocksums: 512 int
    //   tmp     : 1.6M uint2 (12.8 MB)
    unsigned short* support = (unsigned short*)d_ws;
    unsigned short* wt = support + (size_t)N_NODES * OUT_F;
    int* counts = (int*)(wt + IN_F * OUT_F);
    int* blocksums = counts + NSCAN;
    uint2* tmp = (uint2*)(blocksums + 512);

    const int NSCAN_BLOCKS = (NSCAN + 1023) / 1024;  // 196

    // dense path
    wtrans_kernel<<<OUT_F, 256, 0, stream>>>(weight, wt);
    gemm_mfma_kernel<<<(N_NODES + 127) / 128, 256, 0, stream>>>(x, wt, support);

    // bucket-grouping counting sort of edges by destination (64-node buckets)
    count_kernel<<<NCHUNK, 256, 0, stream>>>(adj_row, counts);
    scan1_kernel<<<NSCAN_BLOCKS, 256, 0, stream>>>(counts, blocksums, NSCAN);
    scan2_kernel<<<1, 256, 0, stream>>>(blocksums, NSCAN_BLOCKS);
    scan3_kernel<<<NSCAN_BLOCKS, 256, 0, stream>>>(counts, blocksums, NSCAN);
    scatter1_kernel<<<NCHUNK, 256, 0, stream>>>(adj_row, adj_col, adj_val, counts, tmp);

    // edge-parallel accumulate per 64-node bucket (LDS f32 atomics)
    accum_bucket_kernel<<<NBUCK, 256, 0, stream>>>(support, tmp, counts, bias, out);
}

// Round 9
// 132.699 us; speedup vs baseline: 9.5213x; 9.5213x over previous
//
#include <hip/hip_runtime.h>

#define N_NODES 100000
#define N_EDGES 1600000
#define IN_F 256
#define OUT_F 128
#define LDK 40  // padded k-stride (bf16 elems) for LDS tiles

// two-level counting sort params (round-6 proven config)
#define NBUCK 391            // ceil(N_NODES / 256): coarse bucket = dst >> 8
#define NCHUNK 256           // edge chunks
#define CHUNK_E (N_EDGES / NCHUNK)  // 6250
#define NSCAN (NBUCK * NCHUNK)      // 100096 count-matrix entries (mult of 16)
#define SCAN_BLK 4096        // elems per scan1 block
#define NSCAN_BLOCKS ((NSCAN + SCAN_BLK - 1) / SCAN_BLK)  // 25

typedef __attribute__((ext_vector_type(8))) short bf16x8;
typedef __attribute__((ext_vector_type(4))) float f32x4;

__device__ __forceinline__ unsigned short f2bf(float f) {
    unsigned u = __float_as_uint(f);
    unsigned r = u + 0x7fffu + ((u >> 16) & 1u);  // RNE
    return (unsigned short)(r >> 16);
}

// ---------------------------------------------------------------------------
// K1: count (blocks 0..255)  ∥  wtrans (blocks 256..383)
// ---------------------------------------------------------------------------
__global__ __launch_bounds__(256) void count_wtrans_kernel(const int* __restrict__ rowi,
                                                           int* __restrict__ counts,
                                                           const float* __restrict__ w,
                                                           unsigned short* __restrict__ wt) {
    const int tid = threadIdx.x;
    if (blockIdx.x >= NCHUNK) {
        int c = blockIdx.x - NCHUNK;  // 0..127
        wt[c * IN_F + tid] = f2bf(w[tid * OUT_F + c]);
        return;
    }
    __shared__ int hist[NBUCK];
    const int c = blockIdx.x;
    for (int i = tid; i < NBUCK; i += 256) hist[i] = 0;
    __syncthreads();
    const int e0 = c * CHUNK_E;
    for (int i = tid; i < CHUNK_E; i += 256)
        atomicAdd(&hist[rowi[e0 + i] >> 8], 1);
    __syncthreads();
    for (int i = tid; i < NBUCK; i += 256) counts[i * NCHUNK + c] = hist[i];
}

// ---------------------------------------------------------------------------
// K2: scan1 — per-block (4096 elems) exclusive scan in place + block sums.
// ---------------------------------------------------------------------------
__global__ __launch_bounds__(256) void scan1_kernel(int* __restrict__ data,
                                                    int* __restrict__ blocksums,
                                                    int n) {
    __shared__ int sdata[256];
    const int tid = threadIdx.x;
    const int base = blockIdx.x * SCAN_BLK + tid * 16;
    int v[16];
    if (base < n) {
#pragma unroll
        for (int q = 0; q < 4; ++q) {
            int4 t = *reinterpret_cast<const int4*>(&data[base + q * 4]);
            v[q * 4 + 0] = t.x; v[q * 4 + 1] = t.y; v[q * 4 + 2] = t.z; v[q * 4 + 3] = t.w;
        }
    } else {
#pragma unroll
        for (int i = 0; i < 16; ++i) v[i] = 0;
    }
    int pre[16], run = 0;
#pragma unroll
    for (int i = 0; i < 16; ++i) { pre[i] = run; run += v[i]; }
    sdata[tid] = run;
    __syncthreads();
#pragma unroll
    for (int off = 1; off < 256; off <<= 1) {
        int t = (tid >= off) ? sdata[tid - off] : 0;
        __syncthreads();
        sdata[tid] += t;
        __syncthreads();
    }
    int excl = (tid == 0) ? 0 : sdata[tid - 1];
    if (base < n) {
#pragma unroll
        for (int q = 0; q < 4; ++q) {
            int4 t = {excl + pre[q * 4 + 0], excl + pre[q * 4 + 1],
                      excl + pre[q * 4 + 2], excl + pre[q * 4 + 3]};
            *reinterpret_cast<int4*>(&data[base + q * 4]) = t;
        }
    }
    if (tid == 255) blocksums[blockIdx.x] = sdata[255];
}

// ---------------------------------------------------------------------------
// K3: scan2 — single block exclusive scan of nblk (<=256) block sums.
// Consumers add blocksums[j >> 12] on the fly (scan3 eliminated).
// ---------------------------------------------------------------------------
__global__ __launch_bounds__(256) void scan2_kernel(int* __restrict__ blocksums, int nblk) {
    __shared__ int sdata[256];
    const int tid = threadIdx.x;
    sdata[tid] = (tid < nblk) ? blocksums[tid] : 0;
    __syncthreads();
#pragma unroll
    for (int off = 1; off < 256; off <<= 1) {
        int t = (tid >= off) ? sdata[tid - off] : 0;
        __syncthreads();
        sdata[tid] += t;
        __syncthreads();
    }
    if (tid < nblk) blocksums[tid] = (tid == 0) ? 0 : sdata[tid - 1];
}

// ---------------------------------------------------------------------------
// K4: scatter1 (blocks 0..255)  ∥  gemm (blocks 256..1037)
// scatter1: coarse scatter into bucket-grouped tmp (no global atomics).
// gemm: support_bf16[N][128] = bf16(x) @ bf16(w), MFMA 16x16x32.
// ---------------------------------------------------------------------------
__global__ __launch_bounds__(256) void gemm_scatter_kernel(const float* __restrict__ x,
                                                           const unsigned short* __restrict__ wt,
                                                           unsigned short* __restrict__ support,
                                                           const int* __restrict__ rowi,
                                                           const int* __restrict__ coli,
                                                           const float* __restrict__ val,
                                                           const int* __restrict__ counts,
                                                           const int* __restrict__ blocksums,
                                                           uint2* __restrict__ tmp) {
    const int tid = threadIdx.x;

    if (blockIdx.x < NCHUNK) {
        // ----- scatter1 -----
        __shared__ int cur[NBUCK];
        const int c = blockIdx.x;
        for (int i = tid; i < NBUCK; i += 256) {
            int j = i * NCHUNK + c;
            cur[i] = counts[j] + blocksums[j >> 12];
        }
        __syncthreads();
        const int e0 = c * CHUNK_E;
        for (int i = tid; i < CHUNK_E; i += 256) {
            int e = e0 + i;
            int dst = rowi[e];
            int b = dst >> 8;
            int pos = atomicAdd(&cur[b], 1);
            tmp[pos] = make_uint2(((unsigned)(dst & 255) << 17) | (unsigned)coli[e],
                                  __float_as_uint(val[e]));
        }
        return;
    }

    // ----- gemm -----
    __shared__ unsigned short xs[128 * LDK];
    __shared__ unsigned short ws[128 * LDK];

    const int lane = tid & 63;
    const int wv = tid >> 6;
    const int wr = (wv >> 1) * 64;
    const int wc = (wv & 1) * 64;
    const int row0 = (blockIdx.x - NCHUNK) * 128;
    const int l15 = lane & 15;
    const int kg = (lane >> 4) * 8;

    f32x4 acc[4][4];
#pragma unroll
    for (int m = 0; m < 4; ++m)
#pragma unroll
        for (int n = 0; n < 4; ++n) acc[m][n] = (f32x4){0.f, 0.f, 0.f, 0.f};

    for (int kt = 0; kt < 8; ++kt) {
        __syncthreads();
#pragma unroll
        for (int i = 0; i < 4; ++i) {
            int idx = tid + 256 * i;
            int r = idx >> 3, q = idx & 7;
            int grow = row0 + r;
            if (grow > N_NODES - 1) grow = N_NODES - 1;
            float4 v = *reinterpret_cast<const float4*>(&x[(size_t)grow * IN_F + kt * 32 + q * 4]);
            ushort4 b;
            b.x = f2bf(v.x); b.y = f2bf(v.y); b.z = f2bf(v.z); b.w = f2bf(v.w);
            *reinterpret_cast<ushort4*>(&xs[r * LDK + q * 4]) = b;
        }
#pragma unroll
        for (int j = 0; j < 2; ++j) {
            int idx = tid + 256 * j;
            int c = idx >> 2, q = idx & 3;
            uint4 v = *reinterpret_cast<const uint4*>(&wt[c * IN_F + kt * 32 + q * 8]);
            *reinterpret_cast<uint4*>(&ws[c * LDK + q * 8]) = v;
        }
        __syncthreads();

        bf16x8 af[4], bfr[4];
#pragma unroll
        for (int m = 0; m < 4; ++m)
            af[m] = *reinterpret_cast<const bf16x8*>(&xs[(wr + m * 16 + l15) * LDK + kg]);
#pragma unroll
        for (int n = 0; n < 4; ++n)
            bfr[n] = *reinterpret_cast<const bf16x8*>(&ws[(wc + n * 16 + l15) * LDK + kg]);
#pragma unroll
        for (int m = 0; m < 4; ++m)
#pragma unroll
            for (int n = 0; n < 4; ++n)
                acc[m][n] = __builtin_amdgcn_mfma_f32_16x16x32_bf16(af[m], bfr[n], acc[m][n], 0, 0, 0);
    }

#pragma unroll
    for (int m = 0; m < 4; ++m) {
#pragma unroll
        for (int r = 0; r < 4; ++r) {
            int row = row0 + wr + m * 16 + (lane >> 4) * 4 + r;
            if (row < N_NODES) {
#pragma unroll
                for (int n = 0; n < 4; ++n) {
                    support[(size_t)row * OUT_F + wc + n * 16 + l15] = f2bf(acc[m][n][r]);
                }
            }
        }
    }
}

// ---------------------------------------------------------------------------
// K5: fine sort within one 256-node bucket; writes per-node end offsets.
// ---------------------------------------------------------------------------
__global__ __launch_bounds__(256) void fine_kernel(const uint2* __restrict__ tmp,
                                                   const int* __restrict__ counts,
                                                   const int* __restrict__ blocksums,
                                                   uint2* __restrict__ pairs,
                                                   int* __restrict__ offsets) {
    __shared__ int hist[256];
    __shared__ int scanb[256];
    __shared__ int cur[256];
    const int tid = threadIdx.x, b = blockIdx.x;
    int j0 = b * NCHUNK;
    const int start = counts[j0] + blocksums[j0 >> 12];
    int end;
    if (b == NBUCK - 1) end = N_EDGES;
    else {
        int j1 = (b + 1) * NCHUNK;
        end = counts[j1] + blocksums[j1 >> 12];
    }

    hist[tid] = 0;
    __syncthreads();
    for (int i = start + tid; i < end; i += 256)
        atomicAdd(&hist[tmp[i].x >> 17], 1);
    __syncthreads();
    int h = hist[tid];
    scanb[tid] = h;
    __syncthreads();
#pragma unroll
    for (int off = 1; off < 256; off <<= 1) {
        int t = (tid >= off) ? scanb[tid - off] : 0;
        __syncthreads();
        scanb[tid] += t;
        __syncthreads();
    }
    cur[tid] = start + scanb[tid] - h;
    int node = (b << 8) + tid;
    if (node < N_NODES) offsets[node] = start + scanb[tid];
    __syncthreads();
    for (int i = start + tid; i < end; i += 256) {
        uint2 u = tmp[i];
        int dl = u.x >> 17;
        int pos = atomicAdd(&cur[dl], 1);
        pairs[pos] = make_uint2(u.x & 0x1FFFFu, u.y);
    }
}

// ---------------------------------------------------------------------------
// K6: accumulate (round-6 proven version): one wave64 per node, 4 edge slots
// x 16 lanes (8 feats each), x2 unroll -> 8 gathers in flight per wave.
// ---------------------------------------------------------------------------
__global__ __launch_bounds__(256) void accum_kernel(const unsigned short* __restrict__ support,
                                                    const uint2* __restrict__ pairs,
                                                    const int* __restrict__ offsets,
                                                    const float* __restrict__ bias,
                                                    float* __restrict__ out) {
    const int node = blockIdx.x * 4 + (threadIdx.x >> 6);
    const int lane = threadIdx.x & 63;
    const int grp = lane >> 4;   // edge slot 0..3
    const int l16 = lane & 15;   // feats l16*8 .. l16*8+7
    if (node >= N_NODES) return;

    const int start = (node == 0) ? 0 : offsets[node - 1];
    const int end = offsets[node];

    float acc[8];
#pragma unroll
    for (int t = 0; t < 8; ++t) acc[t] = 0.f;

    int j = start + grp;
    for (; j + 4 < end; j += 8) {
        uint2 p0 = pairs[j];
        uint2 p1 = pairs[j + 4];
        uint4 s0 = *reinterpret_cast<const uint4*>(&support[(size_t)p0.x * OUT_F + l16 * 8]);
        uint4 s1 = *reinterpret_cast<const uint4*>(&support[(size_t)p1.x * OUT_F + l16 * 8]);
        float v0 = __uint_as_float(p0.y);
        float v1 = __uint_as_float(p1.y);
        unsigned u0[4] = {s0.x, s0.y, s0.z, s0.w};
        unsigned u1[4] = {s1.x, s1.y, s1.z, s1.w};
#pragma unroll
        for (int q = 0; q < 4; ++q) {
            acc[2 * q + 0] += __uint_as_float(u0[q] << 16) * v0;
            acc[2 * q + 1] += __uint_as_float(u0[q] & 0xffff0000u) * v0;
            acc[2 * q + 0] += __uint_as_float(u1[q] << 16) * v1;
            acc[2 * q + 1] += __uint_as_float(u1[q] & 0xffff0000u) * v1;
        }
    }
    for (; j < end; j += 4) {
        uint2 p0 = pairs[j];
        uint4 s0 = *reinterpret_cast<const uint4*>(&support[(size_t)p0.x * OUT_F + l16 * 8]);
        float v0 = __uint_as_float(p0.y);
        unsigned u0[4] = {s0.x, s0.y, s0.z, s0.w};
#pragma unroll
        for (int q = 0; q < 4; ++q) {
            acc[2 * q + 0] += __uint_as_float(u0[q] << 16) * v0;
            acc[2 * q + 1] += __uint_as_float(u0[q] & 0xffff0000u) * v0;
        }
    }

#pragma unroll
    for (int t = 0; t < 8; ++t) {
        acc[t] += __shfl_xor(acc[t], 16);
        acc[t] += __shfl_xor(acc[t], 32);
    }

    if (grp == 0) {
        float4 b0 = *reinterpret_cast<const float4*>(&bias[l16 * 8]);
        float4 b1 = *reinterpret_cast<const float4*>(&bias[l16 * 8 + 4]);
        f32x4 o0 = {acc[0] + b0.x, acc[1] + b0.y, acc[2] + b0.z, acc[3] + b0.w};
        f32x4 o1 = {acc[4] + b1.x, acc[5] + b1.y, acc[6] + b1.z, acc[7] + b1.w};
        f32x4* op = reinterpret_cast<f32x4*>(&out[(size_t)node * OUT_F + l16 * 8]);
        __builtin_nontemporal_store(o0, op);
        __builtin_nontemporal_store(o1, op + 1);
    }
}

extern "C" void kernel_launch(void* const* d_in, const int* in_sizes, int n_in,
                              void* d_out, int out_size, void* d_ws, size_t ws_size,
                              hipStream_t stream) {
    const float* x       = (const float*)d_in[0];
    const float* weight  = (const float*)d_in[1];
    const float* bias    = (const float*)d_in[2];
    const float* adj_val = (const float*)d_in[3];
    const int*   adj_row = (const int*)d_in[4];
    const int*   adj_col = (const int*)d_in[5];
    float* out = (float*)d_out;

    // workspace layout (~52 MB):
    //   support   : 12.8M ushort (25.6 MB)
    //   wt        : 32768 ushort (64 KB)
    //   counts    : 100096 int (scanned in place, block-local)
    //   blocksums : 32 int
    //   offsets   : 100000 int
    //   tmp       : 1.6M uint2 (12.8 MB)
    //   pairs     : 1.6M uint2 (12.8 MB)
    unsigned short* support = (unsigned short*)d_ws;
    unsigned short* wt = support + (size_t)N_NODES * OUT_F;
    int* counts = (int*)(wt + IN_F * OUT_F);
    int* blocksums = counts + NSCAN;
    int* offsets = blocksums + 32;
    uint2* tmp = (uint2*)(offsets + 100000);  // 100096+32+100000 ints = even -> 8B ok
    uint2* pairs = tmp + N_EDGES;

    // K1: count ∥ wtrans
    count_wtrans_kernel<<<NCHUNK + OUT_F, 256, 0, stream>>>(adj_row, counts, weight, wt);
    // K2/K3: scan
    scan1_kernel<<<NSCAN_BLOCKS, 256, 0, stream>>>(counts, blocksums, NSCAN);
    scan2_kernel<<<1, 256, 0, stream>>>(blocksums, NSCAN_BLOCKS);
    // K4: scatter1 ∥ gemm
    gemm_scatter_kernel<<<NCHUNK + (N_NODES + 127) / 128, 256, 0, stream>>>(
        x, wt, support, adj_row, adj_col, adj_val, counts, blocksums, tmp);
    // K5: fine sort per bucket
    fine_kernel<<<NBUCK, 256, 0, stream>>>(tmp, counts, blocksums, pairs, offsets);
    // K6: accumulate per destination node
    accum_kernel<<<(N_NODES + 3) / 4, 256, 0, stream>>>(support, pairs, offsets, bias, out);
}